// Round 1
// baseline (176.348 us; speedup 1.0000x reference)
//
#include <hip/hip_runtime.h>
#include <hip/hip_bf16.h>

#define B_ 256
#define L_ 225
#define D_ 1280
#define H_ 256
#define U_ 256
#define M_ (B_*L_)      // 57600 = 900*64

#define BM 64
#define BN 256
#define BK 64

typedef __bf16  bf16x8 __attribute__((ext_vector_type(8)));
typedef float   f32x4  __attribute__((ext_vector_type(4)));
typedef unsigned short u16x8 __attribute__((ext_vector_type(8)));

__device__ __forceinline__ unsigned short f2bf(float f) {
    __hip_bfloat16 h = __float2bfloat16(f);   // RNE
    union { __hip_bfloat16 h; unsigned short u; } cv;
    cv.h = h;
    return cv.u;
}

// ---------------- kernel 1: W1 [D][U] f32 -> W1t [U][D] bf16 ----------------
__global__ void k_prep_w1t(const float* __restrict__ W1, __hip_bfloat16* __restrict__ w1t) {
    int idx = blockIdx.x * 256 + threadIdx.x;   // 0 .. U_*D_-1, idx = k*U_+u
    int k = idx / U_;
    int u = idx % U_;
    w1t[(size_t)u * D_ + k] = __float2bfloat16(W1[idx]);
}

// ---------------- kernel 2: ph[b][u] = hidden[b] . W2[:,u] + b1[u] + b2[u] ----
__global__ void k_proj_h(const float* __restrict__ hidden, const float* __restrict__ W2,
                         const float* __restrict__ b1, const float* __restrict__ b2,
                         float* __restrict__ ph) {
    __shared__ float sh[H_];
    int b = blockIdx.x;
    int u = threadIdx.x;
    sh[u] = hidden[b * H_ + u];
    __syncthreads();
    float acc = b1[u] + b2[u];
#pragma unroll 8
    for (int h = 0; h < H_; ++h) acc += sh[h] * W2[h * U_ + u];
    ph[b * U_ + u] = acc;
}

// ---------------- kernel 3: fused GEMM + tanh + V-dot -> logits[m] ----------
// 900 blocks x 256 threads. Tile BM=64 x BN=256, full K accumulation.
// Wave w -> (wr=w>>1, wc=w&1): rows [wr*32,+32), cols [wc*128,+128).
__global__ __launch_bounds__(256) void k_gemm_logits(
        const float* __restrict__ feat,
        const __hip_bfloat16* __restrict__ w1t,
        const float* __restrict__ ph,
        const float* __restrict__ Vv,
        float* __restrict__ logits) {
    __shared__ unsigned short sA[BM * BK];   // 8 KB, XOR-swizzled rows (128 B stride)
    __shared__ unsigned short sB[BN * BK];   // 32 KB, XOR-swizzled rows
    __shared__ float sV[U_];
    __shared__ float sL[2][BM];

    const int tid  = threadIdx.x;
    const int lane = tid & 63;
    const int wave = tid >> 6;
    const int wr   = wave >> 1;
    const int wc   = wave & 1;
    const int m0   = blockIdx.x * BM;

    sV[tid] = Vv[tid];   // U_ == blockDim.x

    f32x4 acc[2][8];
#pragma unroll
    for (int mi = 0; mi < 2; ++mi)
#pragma unroll
        for (int ni = 0; ni < 8; ++ni)
            acc[mi][ni] = (f32x4){0.f, 0.f, 0.f, 0.f};

    const char* sAc = (const char*)sA;
    const char* sBc = (const char*)sB;

    for (int kt = 0; kt < D_ / BK; ++kt) {
        const int k0 = kt * BK;
        __syncthreads();   // previous iter's reads done (and sV on iter 0)

        // --- stage A: 64 rows x 64 f32 -> bf16, swizzled. 512 chunks of 8 f32.
#pragma unroll
        for (int i = 0; i < 2; ++i) {
            int c  = tid + i * 256;
            int r  = c >> 3;
            int c8 = c & 7;
            const float* src = feat + (size_t)(m0 + r) * D_ + k0 + (c8 << 3);
            f32x4 v0 = *reinterpret_cast<const f32x4*>(src);
            f32x4 v1 = *reinterpret_cast<const f32x4*>(src + 4);
            u16x8 w;
            w[0] = f2bf(v0[0]); w[1] = f2bf(v0[1]); w[2] = f2bf(v0[2]); w[3] = f2bf(v0[3]);
            w[4] = f2bf(v1[0]); w[5] = f2bf(v1[1]); w[6] = f2bf(v1[2]); w[7] = f2bf(v1[3]);
            int byteoff = (r << 7) + (((c8 << 4)) ^ ((r & 7) << 4));
            *reinterpret_cast<u16x8*>((char*)sAc + byteoff) = w;
        }
        // --- stage B: 256 rows x 64 bf16, already bf16, swizzled. 2048 16B chunks.
#pragma unroll
        for (int i = 0; i < 8; ++i) {
            int c  = tid + i * 256;
            int u  = c >> 3;
            int c8 = c & 7;
            u16x8 w = *reinterpret_cast<const u16x8*>(w1t + (size_t)u * D_ + k0 + (c8 << 3));
            int byteoff = (u << 7) + (((c8 << 4)) ^ ((u & 7) << 4));
            *reinterpret_cast<u16x8*>((char*)sBc + byteoff) = w;
        }
        __syncthreads();

        // --- compute: 2 MFMA k-steps of 32
#pragma unroll
        for (int ks = 0; ks < 2; ++ks) {
            const int kk2 = (ks * 32 + ((lane >> 4) << 3)) * 2;   // byte offset of k within row
            bf16x8 a[2], bb[8];
#pragma unroll
            for (int mi = 0; mi < 2; ++mi) {
                int r = wr * 32 + mi * 16 + (lane & 15);
                a[mi] = *reinterpret_cast<const bf16x8*>(sAc + (r << 7) + (kk2 ^ ((r & 7) << 4)));
            }
#pragma unroll
            for (int ni = 0; ni < 8; ++ni) {
                int u = wc * 128 + ni * 16 + (lane & 15);
                bb[ni] = *reinterpret_cast<const bf16x8*>(sBc + (u << 7) + (kk2 ^ ((u & 7) << 4)));
            }
#pragma unroll
            for (int mi = 0; mi < 2; ++mi)
#pragma unroll
                for (int ni = 0; ni < 8; ++ni)
                    acc[mi][ni] = __builtin_amdgcn_mfma_f32_16x16x32_bf16(
                        a[mi], bb[ni], acc[mi][ni], 0, 0, 0);
        }
    }

    // --- epilogue: tanh(acc + ph) * V, reduce over u, write logits ---
#pragma unroll
    for (int mi = 0; mi < 2; ++mi) {
#pragma unroll
        for (int rg = 0; rg < 4; ++rg) {
            int rloc = wr * 32 + mi * 16 + ((lane >> 4) << 2) + rg;
            int m = m0 + rloc;
            int b = m / L_;
            const float* phr = ph + b * U_;
            float s = 0.f;
#pragma unroll
            for (int ni = 0; ni < 8; ++ni) {
                int u = wc * 128 + ni * 16 + (lane & 15);
                float val = tanhf(acc[mi][ni][rg] + phr[u]);
                s += val * sV[u];
            }
            // reduce across the 16 lanes sharing (lane>>4)
            s += __shfl_xor(s, 1, 64);
            s += __shfl_xor(s, 2, 64);
            s += __shfl_xor(s, 4, 64);
            s += __shfl_xor(s, 8, 64);
            if ((lane & 15) == 0) sL[wc][rloc] = s;
        }
    }
    __syncthreads();
    if (tid < BM) logits[m0 + tid] = sL[0][tid] + sL[1][tid];
}

// ---------------- kernel 4: softmax over L per b ----------------
__global__ void k_softmax(const float* __restrict__ logits, float* __restrict__ attn) {
    __shared__ float red[4];
    int b = blockIdx.x;
    int t = threadIdx.x;
    int lane = t & 63, wave = t >> 6;
    float x = (t < L_) ? logits[b * L_ + t] : -1e30f;

    float mx = x;
#pragma unroll
    for (int off = 32; off > 0; off >>= 1) mx = fmaxf(mx, __shfl_xor(mx, off, 64));
    if (lane == 0) red[wave] = mx;
    __syncthreads();
    mx = fmaxf(fmaxf(red[0], red[1]), fmaxf(red[2], red[3]));
    __syncthreads();

    float e = (t < L_) ? expf(x - mx) : 0.f;
    float sm = e;
#pragma unroll
    for (int off = 32; off > 0; off >>= 1) sm += __shfl_xor(sm, off, 64);
    if (lane == 0) red[wave] = sm;
    __syncthreads();
    sm = red[0] + red[1] + red[2] + red[3];

    if (t < L_) attn[b * L_ + t] = e / sm;
}

// ---------------- kernel 5: context partials (5-way split over L) ----------
// grid (B_, 5), block 320 threads; thread owns one float4 of D.
__global__ void k_ctx_partial(const float* __restrict__ feat, const float* __restrict__ attn,
                              float* __restrict__ part) {
    int b = blockIdx.x;
    int s = blockIdx.y;
    int t = threadIdx.x;          // 0..319
    f32x4 acc = (f32x4){0.f, 0.f, 0.f, 0.f};
    int l0 = s * 45;
#pragma unroll 5
    for (int i = 0; i < 45; ++i) {
        int l = l0 + i;
        float a = attn[b * L_ + l];
        f32x4 f = *reinterpret_cast<const f32x4*>(feat + (size_t)(b * L_ + l) * D_ + t * 4);
        acc += a * f;
    }
    *reinterpret_cast<f32x4*>(part + ((size_t)s * B_ + b) * D_ + t * 4) = acc;
}

// ---------------- kernel 6: reduce 5 partials -> context ----------------
__global__ void k_ctx_reduce(const float* __restrict__ part, float* __restrict__ out) {
    int idx = blockIdx.x * 256 + threadIdx.x;    // float4 index, 81920 total
    f32x4 s = (f32x4){0.f, 0.f, 0.f, 0.f};
#pragma unroll
    for (int sp = 0; sp < 5; ++sp)
        s += *reinterpret_cast<const f32x4*>(part + (size_t)sp * B_ * D_ + (size_t)idx * 4);
    *reinterpret_cast<f32x4*>(out + (size_t)idx * 4) = s;
}

extern "C" void kernel_launch(void* const* d_in, const int* in_sizes, int n_in,
                              void* d_out, int out_size, void* d_ws, size_t ws_size,
                              hipStream_t stream) {
    const float* feat   = (const float*)d_in[0];
    const float* hidden = (const float*)d_in[1];
    const float* W1     = (const float*)d_in[2];
    const float* b1     = (const float*)d_in[3];
    const float* W2     = (const float*)d_in[4];
    const float* b2     = (const float*)d_in[5];
    const float* Vv     = (const float*)d_in[6];
    // bV (d_in[7]) is a scalar shift on logits -> softmax-invariant; skipped.

    char* ws = (char*)d_ws;
    __hip_bfloat16* w1t = (__hip_bfloat16*)(ws);                 // 655360 B
    float* ph     = (float*)(ws + 655360);                       // 262144 B
    float* logits = (float*)(ws + 655360 + 262144);              // 230400 B
    float* attn   = (float*)(ws + 655360 + 262144 + 230400);     // 230400 B
    float* part   = (float*)(ws + 655360 + 262144 + 230400 + 230400); // 6553600 B
    float* out    = (float*)d_out;

    k_prep_w1t   <<<(U_ * D_) / 256, 256, 0, stream>>>(W1, w1t);
    k_proj_h     <<<B_, U_, 0, stream>>>(hidden, W2, b1, b2, ph);
    k_gemm_logits<<<M_ / BM, 256, 0, stream>>>(feat, w1t, ph, Vv, logits);
    k_softmax    <<<B_, 256, 0, stream>>>(logits, attn);
    k_ctx_partial<<<dim3(B_, 5), 320, 0, stream>>>(feat, attn, part);
    k_ctx_reduce <<<(B_ * D_ / 4) / 256, 256, 0, stream>>>(part, out);
}

// Round 2
// 139.060 us; speedup vs baseline: 1.2681x; 1.2681x over previous
//
#include <hip/hip_runtime.h>
#include <hip/hip_bf16.h>

#define B_ 256
#define L_ 225
#define D_ 1280
#define H_ 256
#define U_ 256

typedef __bf16  bf16x8 __attribute__((ext_vector_type(8)));
typedef float   f32x4  __attribute__((ext_vector_type(4)));
typedef unsigned short u16x8 __attribute__((ext_vector_type(8)));

__device__ __forceinline__ unsigned short f2bf(float f) {
    union { __hip_bfloat16 h; unsigned short u; } cv;
    cv.h = __float2bfloat16(f);   // RNE
    return cv.u;
}

__device__ __forceinline__ void gload_lds16(const void* g, void* l) {
    __builtin_amdgcn_global_load_lds(
        (const __attribute__((address_space(1))) unsigned int*)g,
        (__attribute__((address_space(3))) unsigned int*)l,
        16, 0, 0);
}

__device__ __forceinline__ float wredmax(float x) {
#pragma unroll
    for (int off = 32; off > 0; off >>= 1) x = fmaxf(x, __shfl_xor(x, off, 64));
    return x;
}
__device__ __forceinline__ float wredsum(float x) {
#pragma unroll
    for (int off = 32; off > 0; off >>= 1) x += __shfl_xor(x, off, 64);
    return x;
}

// ---------------- kernel 1: W1 [D][U] f32 -> W1t [U][D] bf16 ----------------
__global__ void k_prep_w1t(const float* __restrict__ W1, __hip_bfloat16* __restrict__ w1t) {
    int idx = blockIdx.x * 256 + threadIdx.x;   // idx = k*U_+u
    int k = idx / U_;
    int u = idx % U_;
    w1t[(size_t)u * D_ + k] = __float2bfloat16(W1[idx]);
}

// ------------- kernel 2: ph[b][u] = hidden[b].W2[:,u] + b1[u] + b2[u] -------
__global__ void k_proj_h(const float* __restrict__ hidden, const float* __restrict__ W2,
                         const float* __restrict__ b1, const float* __restrict__ b2,
                         float* __restrict__ ph) {
    __shared__ float sh[H_];
    int b = blockIdx.x;
    int u = threadIdx.x;
    sh[u] = hidden[b * H_ + u];
    __syncthreads();
    float acc = b1[u] + b2[u];
#pragma unroll 8
    for (int h = 0; h < H_; ++h) acc += sh[h] * W2[h * U_ + u];
    ph[b * U_ + u] = acc;
}

// ---------------- kernel 3: fully fused per-batch kernel --------------------
// 256 blocks (1/CU) x 1024 threads. Block b: GEMM(225x256x1280) -> tanh*V ->
// softmax -> context, features read from HBM once (phase-3 re-read is L3-warm).
// LDS layout (bytes):
//   [0, 65536)        stage buf0: A(32K) + B(32K)      (phase 3: pc[16][1280] f32)
//   [65536, 131072)   stage buf1
//   131072  sV[256] f32
//   132096  sPh[256] f32
//   133120  sL[4][256] f32
//   137216  sLog[256] f32
//   138240  sAtt[256] f32
//   139264  sRed[16], 139328 sRed2[16]
__global__ __launch_bounds__(1024, 4) void k_fused(
        const float* __restrict__ feat,
        const __hip_bfloat16* __restrict__ w1t,
        const float* __restrict__ ph,
        const float* __restrict__ Vv,
        float* __restrict__ out) {
    __shared__ __align__(128) char smem[139392];
    float* sV   = (float*)(smem + 131072);
    float* sPh  = (float*)(smem + 132096);
    float* sL   = (float*)(smem + 133120);
    float* sLog = (float*)(smem + 137216);
    float* sAtt = (float*)(smem + 138240);
    float* sRed = (float*)(smem + 139264);
    float* sRed2= (float*)(smem + 139328);

    const int tid  = threadIdx.x;
    const int lane = tid & 63;
    const int wave = tid >> 6;     // 0..15
    const int wr   = wave >> 2;    // 0..3 -> rows [wr*64, +64)
    const int wc   = wave & 3;     // 0..3 -> cols [wc*64, +64)
    const int b    = blockIdx.x;

    if (tid < 256) { sV[tid] = Vv[tid]; sPh[tid] = ph[b * 256 + tid]; }

    // A staging map: thread -> (row ar, k-segment of 16)
    const int ar    = tid >> 2;                 // 0..255
    const int arc   = ar < L_ ? ar : (L_ - 1);  // clamp padded rows
    const int akseg = (tid & 3) << 4;           // 0,16,32,48
    const float* aSrc0 = feat + ((size_t)(b * L_ + arc) * D_ + akseg);
    const int ac80  = akseg >> 3;
    char* const aDst0 = smem;  // offset within buffer computed per call

    f32x4 acc[4][4];
#pragma unroll
    for (int mi = 0; mi < 4; ++mi)
#pragma unroll
        for (int ni = 0; ni < 4; ++ni)
            acc[mi][ni] = (f32x4){0.f, 0.f, 0.f, 0.f};

    auto stage = [&](int kt, char* bufA, char* bufB) {
        const float* src = aSrc0 + kt * 64;
        f32x4 v0 = *reinterpret_cast<const f32x4*>(src);
        f32x4 v1 = *reinterpret_cast<const f32x4*>(src + 4);
        f32x4 v2 = *reinterpret_cast<const f32x4*>(src + 8);
        f32x4 v3 = *reinterpret_cast<const f32x4*>(src + 12);
        // B: global_load_lds, linear LDS dest + inverse-swizzled global source
#pragma unroll
        for (int pass = 0; pass < 2; ++pass) {
            int s   = pass * 1024 + tid;
            int u   = s >> 3;
            int c8s = s & 7;
            int c8g = c8s ^ (u & 7);
            gload_lds16(w1t + (size_t)u * D_ + kt * 64 + c8g * 8, bufB + s * 16);
        }
        u16x8 w0, w1;
        w0[0] = f2bf(v0[0]); w0[1] = f2bf(v0[1]); w0[2] = f2bf(v0[2]); w0[3] = f2bf(v0[3]);
        w0[4] = f2bf(v1[0]); w0[5] = f2bf(v1[1]); w0[6] = f2bf(v1[2]); w0[7] = f2bf(v1[3]);
        w1[0] = f2bf(v2[0]); w1[1] = f2bf(v2[1]); w1[2] = f2bf(v2[2]); w1[3] = f2bf(v2[3]);
        w1[4] = f2bf(v3[0]); w1[5] = f2bf(v3[1]); w1[6] = f2bf(v3[2]); w1[7] = f2bf(v3[3]);
        int swz = (ar & 7) << 4;
        *reinterpret_cast<u16x8*>(bufA + (ar << 7) + ((ac80 << 4) ^ swz))       = w0;
        *reinterpret_cast<u16x8*>(bufA + (ar << 7) + (((ac80 + 1) << 4) ^ swz)) = w1;
    };

    auto compute = [&](const char* bufA, const char* bufB) {
#pragma unroll
        for (int ks = 0; ks < 2; ++ks) {
            const int kk2 = (ks * 32 + ((lane >> 4) << 3)) * 2;
            bf16x8 a[4], bb[4];
#pragma unroll
            for (int mi = 0; mi < 4; ++mi) {
                int r = wr * 64 + mi * 16 + (lane & 15);
                a[mi] = *reinterpret_cast<const bf16x8*>(bufA + (r << 7) + (kk2 ^ ((r & 7) << 4)));
            }
#pragma unroll
            for (int ni = 0; ni < 4; ++ni) {
                int u = wc * 64 + ni * 16 + (lane & 15);
                bb[ni] = *reinterpret_cast<const bf16x8*>(bufB + (u << 7) + (kk2 ^ ((u & 7) << 4)));
            }
#pragma unroll
            for (int mi = 0; mi < 4; ++mi)
#pragma unroll
                for (int ni = 0; ni < 4; ++ni)
                    acc[mi][ni] = __builtin_amdgcn_mfma_f32_16x16x32_bf16(
                        a[mi], bb[ni], acc[mi][ni], 0, 0, 0);
        }
    };

    // ---- phase 1: K-streamed GEMM, double-buffered ----
    stage(0, smem, smem + 32768);
    __syncthreads();
    int cur = 0;
    for (int kt = 0; kt < 20; ++kt) {
        char* An = smem + (cur ^ 1) * 65536;
        if (kt < 19) stage(kt + 1, An, An + 32768);
        char* Ac = smem + cur * 65536;
        compute(Ac, Ac + 32768);
        __syncthreads();
        cur ^= 1;
    }

    // ---- epilogue: tanh(acc+ph)*V, row-reduce -> logits in LDS ----
    float phu[4], vu[4];
#pragma unroll
    for (int ni = 0; ni < 4; ++ni) {
        int u = wc * 64 + ni * 16 + (lane & 15);
        phu[ni] = sPh[u];
        vu[ni]  = sV[u];
    }
#pragma unroll
    for (int mi = 0; mi < 4; ++mi) {
#pragma unroll
        for (int rg = 0; rg < 4; ++rg) {
            int row = wr * 64 + mi * 16 + ((lane >> 4) << 2) + rg;
            float s = 0.f;
#pragma unroll
            for (int ni = 0; ni < 4; ++ni) {
                float x = acc[mi][ni][rg] + phu[ni];
                float t = 1.f - 2.f / (__expf(2.f * x) + 1.f);   // tanh(x)
                s += t * vu[ni];
            }
            s += __shfl_xor(s, 1, 64);
            s += __shfl_xor(s, 2, 64);
            s += __shfl_xor(s, 4, 64);
            s += __shfl_xor(s, 8, 64);
            if ((lane & 15) == 0) sL[wc * 256 + row] = s;
        }
    }
    __syncthreads();
    if (tid < 256) sLog[tid] = sL[tid] + sL[256 + tid] + sL[512 + tid] + sL[768 + tid];
    __syncthreads();

    // ---- softmax over L in LDS ----
    float x  = (tid < L_) ? sLog[tid] : -3.4e38f;
    float mx = wredmax(x);
    if (lane == 0) sRed[wave] = mx;
    __syncthreads();
    mx = sRed[0];
#pragma unroll
    for (int i = 1; i < 16; ++i) mx = fmaxf(mx, sRed[i]);
    float e  = (tid < L_) ? __expf(x - mx) : 0.f;
    float sm = wredsum(e);
    if (lane == 0) sRed2[wave] = sm;
    __syncthreads();
    sm = 0.f;
#pragma unroll
    for (int i = 0; i < 16; ++i) sm += sRed2[i];
    if (tid < L_) sAtt[tid] = e / sm;
    __syncthreads();

    // ---- phase 3: context = attn^T * features (features re-read, L3-warm) --
    f32x4 c[5];
#pragma unroll
    for (int ch = 0; ch < 5; ++ch) c[ch] = (f32x4){0.f, 0.f, 0.f, 0.f};
    for (int l = wave; l < L_; l += 16) {
        float a = sAtt[l];
        const float* fr = feat + (size_t)(b * L_ + l) * D_ + (lane << 2);
#pragma unroll
        for (int ch = 0; ch < 5; ++ch)
            c[ch] += a * *reinterpret_cast<const f32x4*>(fr + ch * 256);
    }
    float* pc = (float*)smem;   // reuse stage buffers: [16][1280] f32
#pragma unroll
    for (int ch = 0; ch < 5; ++ch)
        *reinterpret_cast<f32x4*>(pc + wave * 1280 + ch * 256 + (lane << 2)) = c[ch];
    __syncthreads();
    if (tid < 320) {
        f32x4 s = (f32x4){0.f, 0.f, 0.f, 0.f};
#pragma unroll
        for (int w = 0; w < 16; ++w)
            s += *reinterpret_cast<const f32x4*>(pc + w * 1280 + (tid << 2));
        *reinterpret_cast<f32x4*>(out + (size_t)b * D_ + (tid << 2)) = s;
    }
}

extern "C" void kernel_launch(void* const* d_in, const int* in_sizes, int n_in,
                              void* d_out, int out_size, void* d_ws, size_t ws_size,
                              hipStream_t stream) {
    const float* feat   = (const float*)d_in[0];
    const float* hidden = (const float*)d_in[1];
    const float* W1     = (const float*)d_in[2];
    const float* b1     = (const float*)d_in[3];
    const float* W2     = (const float*)d_in[4];
    const float* b2     = (const float*)d_in[5];
    const float* Vv     = (const float*)d_in[6];
    // bV (d_in[7]) is a uniform logit shift -> softmax-invariant; skipped.

    char* ws = (char*)d_ws;
    __hip_bfloat16* w1t = (__hip_bfloat16*)(ws);        // 655360 B
    float* ph = (float*)(ws + 655360);                  // 262144 B
    float* out = (float*)d_out;

    k_prep_w1t<<<(U_ * D_) / 256, 256, 0, stream>>>(W1, w1t);
    k_proj_h  <<<B_, U_, 0, stream>>>(hidden, W2, b1, b2, ph);
    k_fused   <<<B_, 1024, 0, stream>>>(feat, w1t, ph, Vv, out);
}